// Round 2
// baseline (514.048 us; speedup 1.0000x reference)
//
#include <hip/hip_runtime.h>
#include <math.h>

#define NPROP 2000
#define RPN_ROW (NPROP * 5)       // 10000 floats per row
#define SC_ROW  (NPROP * 2)       // 4000 floats per row
#define PANELTY_K 0.055f
#define HANN_W 0.42f
#define PI_F 3.14159265358979323846f

// LDS staging geometry: 2 chunks of 1000 proposals per row.
#define CHUNK   1000
#define RPN_F4  (CHUNK * 5 / 4)   // 1250 float4 of rpn per chunk
#define SC_F4   (CHUNK * 2 / 4)   // 500 float4 of scores per chunk
#define STG_F4  (RPN_F4 + SC_F4)  // 1750 staged float4 per chunk
#define STG_PAD 1752              // rounded to x8 so the XOR swizzle stays in-bounds

typedef float f4 __attribute__((ext_vector_type(4)));

// Self-inverse XOR swizzle at float4 granularity: flips low3 bits by the next 3.
// Breaks the stride-80B (20-dword) 8-way bank aliasing of the compute-phase
// ds_read_b128s while keeping staging writes a dense permutation (conflict-free).
__device__ __forceinline__ int swz(int idx) { return idx ^ ((idx >> 3) & 7); }

// One block per row; 256 threads.
// v2 change vs the 503us kernel: the old direct-load scan issued float4 loads
// whose lanes stride by 80B (one 5-f4 record group per thread), so each VMEM
// instruction touched ~60 distinct cache lines instead of 16 — address
// divergence, not DRAM, was the limiter (~2.5 TB/s effective). Now each chunk
// is staged to LDS with flat k=tid+256*it float4 loads (16B/lane, fully
// coalesced), and the 80B record reads happen in LDS. eval() arithmetic is
// bit-identical to the reference-matching version — do not touch it.
__global__ __launch_bounds__(256) void trnms_kernel(
    const float* __restrict__ rois,      // (N,4)
    const float* __restrict__ rpn,       // (N,NPROP,5)
    const float* __restrict__ scores,    // (N,NPROP,2)
    float* __restrict__ out_rois,        // (N,4)
    float* __restrict__ out_scores)      // (N,1)
{
    const int i   = blockIdx.x;
    const int tid = threadIdx.x;

    __shared__ f4    stg[STG_PAD];   // 28,032 B -> 5 blocks/CU (LDS-bound)
    __shared__ float sval[4];
    __shared__ int   sidx[4];

    // Reference ROI stats (identical expression order to numpy reference)
    const float rx1 = rois[i * 4 + 0], ry1 = rois[i * 4 + 1];
    const float rx2 = rois[i * 4 + 2], ry2 = rois[i * 4 + 3];
    const float x = (rx1 + rx2) * 0.5f;
    const float y = (ry1 + ry2) * 0.5f;
    const float w = fabsf(rx1 - rx2) + 0.0001f;
    const float h = fabsf(ry1 - ry2) + 0.0001f;
    const float p = (w + h) * 0.5f;
    const float s = sqrtf((w + p) * (h + p));
    const float ratio = w / h;
    const float r_max = fmaxf(ratio, 1.0f / ratio);
    const float window = s * 2.0f;

    const float* __restrict__ rowr  = rpn    + (long long)i * RPN_ROW;
    const float* __restrict__ rowsc = scores + (long long)i * SC_ROW;
    const f4* __restrict__ rowr4  = (const f4*)rowr;
    const f4* __restrict__ rowsc4 = (const f4*)rowsc;

    float best  = -INFINITY;
    int   besti = 0x7fffffff;

    // j strictly increases in processing order within a thread (chunk 0 then
    // chunk 1, same thread -> same lane), so strict '>' keeps the earliest
    // index (numpy argmax tie-break).
    auto eval = [&](float px1, float py1, float px2, float py2, float scj, int j) {
        const float x_ = (px1 + px2) * 0.5f;
        const float y_ = (py1 + py2) * 0.5f;
        const float w_ = fabsf(px1 - px2) + 0.0001f;
        const float h_ = fabsf(py1 - py2) + 0.0001f;
        const float p_ = (w_ + h_) * 0.5f;
        const float s_ = sqrtf((w_ + p_) * (h_ + p_));
        const float smax = fmaxf(s / s_, s_ / s);
        const float pen  = expf(-PANELTY_K * (smax * r_max - 1.0f));
        const float dx = x - x_;
        const float dy = y - y_;
        const float dist = sqrtf(dx * dx + dy * dy);
        float han = 0.5f + 0.5f * cosf(dist * PI_F / window);
        han = (dist > window) ? 0.0f : han;
        const float val = scj * pen + han * HANN_W;
        if (val > best) { best = val; besti = j; }
    };

    for (int c = 0; c < 2; ++c) {
        // ---- stage chunk c: fully coalesced float4 stream -> LDS ----
        const f4* __restrict__ src_r = rowr4  + c * RPN_F4;
        const f4* __restrict__ src_s = rowsc4 + c * SC_F4;
        for (int k = tid; k < STG_F4; k += 256) {
            const f4 v = (k < RPN_F4) ? src_r[k] : src_s[k - RPN_F4];
            stg[swz(k)] = v;
        }
        __syncthreads();

        // ---- compute: 250 groups of 4 proposals, threads 250..255 idle ----
        if (tid < CHUNK / 4) {
            const int g  = tid;
            const int j0 = c * CHUNK + g * 4;
            const int gb = g * 5;
            const f4 v0 = stg[swz(gb + 0)];
            const f4 v1 = stg[swz(gb + 1)];
            const f4 v2 = stg[swz(gb + 2)];
            const f4 v3 = stg[swz(gb + 3)];
            const f4 v4 = stg[swz(gb + 4)];
            const f4 s0 = stg[swz(RPN_F4 + g * 2 + 0)];
            const f4 s1 = stg[swz(RPN_F4 + g * 2 + 1)];

            eval(v0.y, v0.z, v0.w, v1.x, s0.y, j0 + 0);
            eval(v1.z, v1.w, v2.x, v2.y, s0.w, j0 + 1);
            eval(v2.w, v3.x, v3.y, v3.z, s1.y, j0 + 2);
            eval(v4.x, v4.y, v4.z, v4.w, s1.w, j0 + 3);
        }
        __syncthreads();   // protect stg before next chunk overwrites it
    }

    // ---- wave-level reduction (64 lanes), first-index tie-break ----
    #pragma unroll
    for (int off = 32; off > 0; off >>= 1) {
        const float ov = __shfl_down(best, off);
        const int   oi = __shfl_down(besti, off);
        if (ov > best || (ov == best && oi < besti)) { best = ov; besti = oi; }
    }

    const int wave = tid >> 6;
    if ((tid & 63) == 0) { sval[wave] = best; sidx[wave] = besti; }
    __syncthreads();

    if (tid == 0) {
        #pragma unroll
        for (int k = 1; k < 4; ++k) {
            const float ov = sval[k];
            const int   oi = sidx[k];
            if (ov > best || (ov == best && oi < besti)) { best = ov; besti = oi; }
        }
        out_rois[i * 4 + 0] = rowr[besti * 5 + 1];
        out_rois[i * 4 + 1] = rowr[besti * 5 + 2];
        out_rois[i * 4 + 2] = rowr[besti * 5 + 3];
        out_rois[i * 4 + 3] = rowr[besti * 5 + 4];
        out_scores[i] = rowsc[besti * 2 + 1];
    }
}

extern "C" void kernel_launch(void* const* d_in, const int* in_sizes, int n_in,
                              void* d_out, int out_size, void* d_ws, size_t ws_size,
                              hipStream_t stream) {
    const float* rois   = (const float*)d_in[0];  // (N,4)
    const float* rpn    = (const float*)d_in[1];  // (N,2000,5)
    const float* scores = (const float*)d_in[2];  // (N,2000,2)

    const int N = in_sizes[0] / 4;  // 8192

    float* out_rois   = (float*)d_out;          // first N*4 floats
    float* out_scores = (float*)d_out + N * 4;  // next N floats

    trnms_kernel<<<N, 256, 0, stream>>>(rois, rpn, scores, out_rois, out_scores);
}

// Round 3
// 505.923 us; speedup vs baseline: 1.0161x; 1.0161x over previous
//
#include <hip/hip_runtime.h>
#include <math.h>

#define NPROP 2000
#define RPN_ROW (NPROP * 5)       // 10000 floats per row
#define SC_ROW  (NPROP * 2)       // 4000 floats per row
#define PANELTY_K 0.055f
#define HANN_W 0.42f
#define PI_F 3.14159265358979323846f

typedef float f4 __attribute__((ext_vector_type(4)));

// One block per row; 256 threads; each thread computes up to 8 proposals
// (two groups of 4) straight from registers.
//
// v3 history: R0 direct-load = 503.4 us. R2 LDS-staged (fully coalesced
// global) = 514.0 us -> global address divergence is NOT the limiter; the
// 7 loads per group reuse the same 80B of cache lines via L1, so HBM traffic
// is already compulsory-minimal (~459 MB) and the kernel sits at the DRAM
// wall. LDS detour only added occupancy loss + barriers. This version
// reverts to direct loads and explicitly issues BOTH chunks' 14 float4
// loads before any eval, maximizing per-thread loads-in-flight at the wall.
// eval() arithmetic is bit-identical to the reference-matching version.
__global__ __launch_bounds__(256) void trnms_kernel(
    const float* __restrict__ rois,      // (N,4)
    const float* __restrict__ rpn,       // (N,NPROP,5)
    const float* __restrict__ scores,    // (N,NPROP,2)
    float* __restrict__ out_rois,        // (N,4)
    float* __restrict__ out_scores)      // (N,1)
{
    const int i   = blockIdx.x;
    const int tid = threadIdx.x;

    const float* __restrict__ rowr  = rpn    + (long long)i * RPN_ROW;
    const float* __restrict__ rowsc = scores + (long long)i * SC_ROW;
    const f4* __restrict__ rowr4  = (const f4*)rowr;
    const f4* __restrict__ rowsc4 = (const f4*)rowsc;

    // ---- issue ALL vector loads up front (chunk A: groups 0..255,
    //      chunk B: groups 256..499, predicated) ----
    const int ga = tid;          // proposals 4*tid .. 4*tid+3
    const int gb = 256 + tid;    // proposals 1024+4*tid .. (valid iff gb < 500)
    const bool hasB = (gb < NPROP / 4);

    const f4 a0 = rowr4[ga * 5 + 0];
    const f4 a1 = rowr4[ga * 5 + 1];
    const f4 a2 = rowr4[ga * 5 + 2];
    const f4 a3 = rowr4[ga * 5 + 3];
    const f4 a4 = rowr4[ga * 5 + 4];
    const f4 sa0 = rowsc4[ga * 2 + 0];
    const f4 sa1 = rowsc4[ga * 2 + 1];

    f4 b0 = {}, b1 = {}, b2 = {}, b3 = {}, b4 = {}, sb0 = {}, sb1 = {};
    if (hasB) {
        b0 = rowr4[gb * 5 + 0];
        b1 = rowr4[gb * 5 + 1];
        b2 = rowr4[gb * 5 + 2];
        b3 = rowr4[gb * 5 + 3];
        b4 = rowr4[gb * 5 + 4];
        sb0 = rowsc4[gb * 2 + 0];
        sb1 = rowsc4[gb * 2 + 1];
    }

    // ---- reference ROI stats (uniform; s_load + scalar-ish math overlaps
    //      the vector loads above). Identical expression order to reference.
    const float rx1 = rois[i * 4 + 0], ry1 = rois[i * 4 + 1];
    const float rx2 = rois[i * 4 + 2], ry2 = rois[i * 4 + 3];
    const float x = (rx1 + rx2) * 0.5f;
    const float y = (ry1 + ry2) * 0.5f;
    const float w = fabsf(rx1 - rx2) + 0.0001f;
    const float h = fabsf(ry1 - ry2) + 0.0001f;
    const float p = (w + h) * 0.5f;
    const float s = sqrtf((w + p) * (h + p));
    const float ratio = w / h;
    const float r_max = fmaxf(ratio, 1.0f / ratio);
    const float window = s * 2.0f;

    float best  = -INFINITY;
    int   besti = 0x7fffffff;

    // j strictly increases in processing order within a thread (group A then
    // group B), so strict '>' keeps the earliest index (numpy argmax
    // tie-break).
    auto eval = [&](float px1, float py1, float px2, float py2, float scj, int j) {
        const float x_ = (px1 + px2) * 0.5f;
        const float y_ = (py1 + py2) * 0.5f;
        const float w_ = fabsf(px1 - px2) + 0.0001f;
        const float h_ = fabsf(py1 - py2) + 0.0001f;
        const float p_ = (w_ + h_) * 0.5f;
        const float s_ = sqrtf((w_ + p_) * (h_ + p_));
        const float smax = fmaxf(s / s_, s_ / s);
        const float pen  = expf(-PANELTY_K * (smax * r_max - 1.0f));
        const float dx = x - x_;
        const float dy = y - y_;
        const float dist = sqrtf(dx * dx + dy * dy);
        float han = 0.5f + 0.5f * cosf(dist * PI_F / window);
        han = (dist > window) ? 0.0f : han;
        const float val = scj * pen + han * HANN_W;
        if (val > best) { best = val; besti = j; }
    };

    {   // chunk A: proposals 4*tid .. 4*tid+3
        const int j0 = ga * 4;
        eval(a0.y, a0.z, a0.w, a1.x, sa0.y, j0 + 0);
        eval(a1.z, a1.w, a2.x, a2.y, sa0.w, j0 + 1);
        eval(a2.w, a3.x, a3.y, a3.z, sa1.y, j0 + 2);
        eval(a4.x, a4.y, a4.z, a4.w, sa1.w, j0 + 3);
    }
    if (hasB) {   // chunk B: proposals 1024+4*tid .. +3
        const int j0 = gb * 4;
        eval(b0.y, b0.z, b0.w, b1.x, sb0.y, j0 + 0);
        eval(b1.z, b1.w, b2.x, b2.y, sb0.w, j0 + 1);
        eval(b2.w, b3.x, b3.y, b3.z, sb1.y, j0 + 2);
        eval(b4.x, b4.y, b4.z, b4.w, sb1.w, j0 + 3);
    }

    // ---- wave-level reduction (64 lanes), first-index tie-break ----
    #pragma unroll
    for (int off = 32; off > 0; off >>= 1) {
        const float ov = __shfl_down(best, off);
        const int   oi = __shfl_down(besti, off);
        if (ov > best || (ov == best && oi < besti)) { best = ov; besti = oi; }
    }

    __shared__ float sval[4];
    __shared__ int   sidx[4];
    const int wave = tid >> 6;
    if ((tid & 63) == 0) { sval[wave] = best; sidx[wave] = besti; }
    __syncthreads();

    if (tid == 0) {
        #pragma unroll
        for (int k = 1; k < 4; ++k) {
            const float ov = sval[k];
            const int   oi = sidx[k];
            if (ov > best || (ov == best && oi < besti)) { best = ov; besti = oi; }
        }
        out_rois[i * 4 + 0] = rowr[besti * 5 + 1];
        out_rois[i * 4 + 1] = rowr[besti * 5 + 2];
        out_rois[i * 4 + 2] = rowr[besti * 5 + 3];
        out_rois[i * 4 + 3] = rowr[besti * 5 + 4];
        out_scores[i] = rowsc[besti * 2 + 1];
    }
}

extern "C" void kernel_launch(void* const* d_in, const int* in_sizes, int n_in,
                              void* d_out, int out_size, void* d_ws, size_t ws_size,
                              hipStream_t stream) {
    const float* rois   = (const float*)d_in[0];  // (N,4)
    const float* rpn    = (const float*)d_in[1];  // (N,2000,5)
    const float* scores = (const float*)d_in[2];  // (N,2000,2)

    const int N = in_sizes[0] / 4;  // 8192

    float* out_rois   = (float*)d_out;          // first N*4 floats
    float* out_scores = (float*)d_out + N * 4;  // next N floats

    trnms_kernel<<<N, 256, 0, stream>>>(rois, rpn, scores, out_rois, out_scores);
}